// Round 2
// baseline (973.310 us; speedup 1.0000x reference)
//
#include <hip/hip_runtime.h>
#include <math.h>

#define EPSN 1e-8f
#define DOUT 10

// ---------------- scatter layer 0: msg[d, 0:64] += x[s, 0:64]; msg[d,64] += 1 ----------------
__global__ void scatter0_kernel(const float* __restrict__ x,
                                const int* __restrict__ src,
                                const int* __restrict__ dst,
                                float* __restrict__ msg, int E) {
    int w = (int)((blockIdx.x * blockDim.x + threadIdx.x) >> 6);
    if (w >= E) return;
    int lane = threadIdx.x & 63;
    int s = src[w], d = dst[w];
    atomicAdd(&msg[d * 65 + lane], x[s * 64 + lane]);
    if (lane == 0) atomicAdd(&msg[d * 65 + 64], 1.0f);
}

// ---------------- layer 0 compute: out = hh@Ws + neigh@Wn, L2-normalize, relu ----------------
// wave per node; lane j computes output dims j and j+64.
__global__ void layer0_kernel(const float* __restrict__ x,
                              const float* __restrict__ msg,
                              const float* __restrict__ Ws,
                              const float* __restrict__ Wn,
                              float* __restrict__ h1, int N) {
    int n = (int)((blockIdx.x * blockDim.x + threadIdx.x) >> 6);
    if (n >= N) return;
    int lane = threadIdx.x & 63;

    float deg   = msg[n * 65 + 64];
    float scale = 1.0f / fmaxf(deg, 1.0f);
    float xv = x[n * 64 + lane];              // lane k holds hh[n,k], k<64
    float mv = msg[n * 65 + lane] * scale;    // lane k holds neigh[n,k], k<64
    float bones = deg * scale;                // neigh[n,64]

    // k = 64 homogeneous term: hh[n,64] = 1
    float acc0 = Ws[64 * 128 + lane]      + Wn[64 * 128 + lane]      * bones;
    float acc1 = Ws[64 * 128 + 64 + lane] + Wn[64 * 128 + 64 + lane] * bones;

#pragma unroll
    for (int k = 0; k < 64; ++k) {
        float a = __shfl(xv, k);
        float b = __shfl(mv, k);
        acc0 = fmaf(a, Ws[k * 128 + lane], acc0);
        acc0 = fmaf(b, Wn[k * 128 + lane], acc0);
        acc1 = fmaf(a, Ws[k * 128 + 64 + lane], acc1);
        acc1 = fmaf(b, Wn[k * 128 + 64 + lane], acc1);
    }

    float ss = acc0 * acc0 + acc1 * acc1;
#pragma unroll
    for (int off = 32; off; off >>= 1) ss += __shfl_xor(ss, off);
    float inv = 1.0f / (sqrtf(ss) + EPSN);

    h1[n * 128 + lane]      = fmaxf(acc0 * inv, 0.0f);
    h1[n * 128 + 64 + lane] = fmaxf(acc1 * inv, 0.0f);
}

// ---------------- scatter layer 1: msg[d, 0:128] += h1[s, 0:128]; msg[d,128] += 1 ----------------
__global__ void scatter1_kernel(const float* __restrict__ h1,
                                const int* __restrict__ src,
                                const int* __restrict__ dst,
                                float* __restrict__ msg, int E) {
    int w = (int)((blockIdx.x * blockDim.x + threadIdx.x) >> 6);
    if (w >= E) return;
    int lane = threadIdx.x & 63;
    int s = src[w], d = dst[w];
    atomicAdd(&msg[d * 129 + lane],      h1[s * 128 + lane]);
    atomicAdd(&msg[d * 129 + 64 + lane], h1[s * 128 + 64 + lane]);
    if (lane == 0) atomicAdd(&msg[d * 129 + 128], 1.0f);
}

// ---------------- layer 1 compute: out = hh1@Ws1 + neigh1@Wn1, normalize, log_softmax ----------------
// wave per node; lane l accumulates K-partials (k=l and k=l+64) for all 10 outputs.
__global__ void layer1_kernel(const float* __restrict__ h1,
                              const float* __restrict__ msg,
                              const float* __restrict__ Ws,
                              const float* __restrict__ Wn,
                              float* __restrict__ out, int N) {
    int n = (int)((blockIdx.x * blockDim.x + threadIdx.x) >> 6);
    if (n >= N) return;
    int lane = threadIdx.x & 63;

    float deg   = msg[n * 129 + 128];
    float scale = 1.0f / fmaxf(deg, 1.0f);
    float a0 = h1[n * 128 + lane];
    float a1 = h1[n * 128 + 64 + lane];
    float b0 = msg[n * 129 + lane] * scale;
    float b1 = msg[n * 129 + 64 + lane] * scale;

    float p[DOUT];
#pragma unroll
    for (int j = 0; j < DOUT; ++j) {
        float v = a0 * Ws[lane * DOUT + j] + b0 * Wn[lane * DOUT + j];
        v = fmaf(a1, Ws[(lane + 64) * DOUT + j], v);
        v = fmaf(b1, Wn[(lane + 64) * DOUT + j], v);
        if (lane == 0) v += Ws[128 * DOUT + j] + (deg * scale) * Wn[128 * DOUT + j];
        p[j] = v;
    }
    // butterfly allreduce each output across the wave
#pragma unroll
    for (int j = 0; j < DOUT; ++j) {
#pragma unroll
        for (int off = 32; off; off >>= 1) p[j] += __shfl_xor(p[j], off);
    }

    float ss = 0.0f;
#pragma unroll
    for (int j = 0; j < DOUT; ++j) ss = fmaf(p[j], p[j], ss);
    float inv = 1.0f / (sqrtf(ss) + EPSN);

    float m = -INFINITY;
#pragma unroll
    for (int j = 0; j < DOUT; ++j) { p[j] *= inv; m = fmaxf(m, p[j]); }
    float se = 0.0f;
#pragma unroll
    for (int j = 0; j < DOUT; ++j) se += expf(p[j] - m);
    float ls = logf(se) + m;

    if (lane < DOUT) {
        float v = 0.0f;
#pragma unroll
        for (int j = 0; j < DOUT; ++j) if (lane == j) v = p[j] - ls;
        out[n * DOUT + lane] = v;
    }
}

extern "C" void kernel_launch(void* const* d_in, const int* in_sizes, int n_in,
                              void* d_out, int out_size, void* d_ws, size_t ws_size,
                              hipStream_t stream) {
    const float* x   = (const float*)d_in[0];
    const int*   ei  = (const int*)d_in[1];
    const float* Ws0 = (const float*)d_in[2];
    const float* Wn0 = (const float*)d_in[3];
    const float* Ws1 = (const float*)d_in[4];
    const float* Wn1 = (const float*)d_in[5];

    int N = in_sizes[0] / 64;
    int E = in_sizes[1] / 2;
    const int* src = ei;
    const int* dst = ei + E;

    char* ws = (char*)d_ws;
    float* h1   = (float*)ws;                             // N*128 f32 (25.6 MB)
    float* msg  = (float*)(ws + (size_t)N * 128 * 4);     // reused: N*65 then N*129 (25.8 MB)
    float* outp = (float*)d_out;

    int ebw = (E + 3) / 4;   // 4 waves (edges) per 256-thread block
    int nbw = (N + 3) / 4;   // 4 waves (nodes) per 256-thread block

    hipMemsetAsync(msg, 0, (size_t)N * 65 * 4, stream);
    scatter0_kernel<<<ebw, 256, 0, stream>>>(x, src, dst, msg, E);
    layer0_kernel<<<nbw, 256, 0, stream>>>(x, msg, Ws0, Wn0, h1, N);

    hipMemsetAsync(msg, 0, (size_t)N * 129 * 4, stream);
    scatter1_kernel<<<ebw, 256, 0, stream>>>(h1, src, dst, msg, E);
    layer1_kernel<<<nbw, 256, 0, stream>>>(h1, msg, Ws1, Wn1, outp, N);
}

// Round 3
// 511.433 us; speedup vs baseline: 1.9031x; 1.9031x over previous
//
#include <hip/hip_runtime.h>
#include <math.h>

#define EPSN 1e-8f
#define DOUT 10

// ================= CSR build =================
__global__ void hist_kernel(const int* __restrict__ dst, int* __restrict__ deg, int E) {
    int e = blockIdx.x * blockDim.x + threadIdx.x;
    if (e < E) atomicAdd(&deg[dst[e]], 1);
}

// single-block exclusive scan of deg[0..N) -> row_ptr[0..N], cursor copy
__global__ void scan_kernel(const int* __restrict__ deg, int* __restrict__ row_ptr,
                            int* __restrict__ cursor, int N) {
    __shared__ int sums[1024];
    int t = threadIdx.x;
    int CH = (N + 1023) >> 10;
    int base = t * CH;
    int local = 0;
    for (int i = 0; i < CH; ++i) {
        int idx = base + i;
        if (idx < N) local += deg[idx];
    }
    sums[t] = local;
    __syncthreads();
    for (int off = 1; off < 1024; off <<= 1) {
        int v = 0;
        if (t >= off) v = sums[t - off];
        __syncthreads();
        if (t >= off) sums[t] += v;
        __syncthreads();
    }
    int run = (t == 0) ? 0 : sums[t - 1];
    for (int i = 0; i < CH; ++i) {
        int idx = base + i;
        if (idx < N) {
            row_ptr[idx] = run;
            cursor[idx]  = run;
            run += deg[idx];
        }
    }
    if (t == 1023) row_ptr[N] = sums[1023];
}

__global__ void fill_kernel(const int* __restrict__ src, const int* __restrict__ dst,
                            int* __restrict__ cursor, int* __restrict__ col, int E) {
    int e = blockIdx.x * blockDim.x + threadIdx.x;
    if (e < E) {
        int pos = atomicAdd(&cursor[dst[e]], 1);
        col[pos] = src[e];
    }
}

// ================= layer 0 fused: CSR-mean aggregate + GEMV + normalize + relu =================
// 8 waves / block; wave per node; lane j owns output dims j and j+64.
__global__ void __launch_bounds__(512)
layer0_fused(const float* __restrict__ x,
             const int* __restrict__ row_ptr, const int* __restrict__ col,
             const float* __restrict__ Ws, const float* __restrict__ Wn,
             float* __restrict__ h1, int N) {
    __shared__ float sWs[65 * 128];
    __shared__ float sWn[65 * 128];
    for (int i = threadIdx.x; i < 65 * 128; i += 512) {
        sWs[i] = Ws[i];
        sWn[i] = Wn[i];
    }
    __syncthreads();

    int n = (int)((blockIdx.x * blockDim.x + threadIdx.x) >> 6);
    if (n >= N) return;
    int lane = threadIdx.x & 63;

    int rs = row_ptr[n], re = row_ptr[n + 1];
    float acc = 0.0f;
    for (int base = rs; base < re; base += 64) {
        int cnt = min(64, re - base);
        int e = 0;
        if (base + lane < re) e = col[base + lane];
        int j = 0;
        for (; j + 3 < cnt; j += 4) {
            int s0 = __shfl(e, j), s1 = __shfl(e, j + 1);
            int s2 = __shfl(e, j + 2), s3 = __shfl(e, j + 3);
            float v0 = x[s0 * 64 + lane], v1 = x[s1 * 64 + lane];
            float v2 = x[s2 * 64 + lane], v3 = x[s3 * 64 + lane];
            acc += v0; acc += v1; acc += v2; acc += v3;
        }
        for (; j < cnt; ++j) {
            int s = __shfl(e, j);
            acc += x[s * 64 + lane];
        }
    }

    float deg   = (float)(re - rs);
    float scale = 1.0f / fmaxf(deg, 1.0f);
    float xv = x[n * 64 + lane];   // hh[n, lane]
    float mv = acc * scale;        // neigh[n, lane]
    float bones = deg * scale;     // neigh[n, 64]

    // k = 64 homogeneous term (hh[n,64] = 1)
    float acc0 = sWs[64 * 128 + lane]      + sWn[64 * 128 + lane]      * bones;
    float acc1 = sWs[64 * 128 + 64 + lane] + sWn[64 * 128 + 64 + lane] * bones;

#pragma unroll
    for (int k = 0; k < 64; ++k) {
        float a = __shfl(xv, k);
        float b = __shfl(mv, k);
        acc0 = fmaf(a, sWs[k * 128 + lane], acc0);
        acc0 = fmaf(b, sWn[k * 128 + lane], acc0);
        acc1 = fmaf(a, sWs[k * 128 + 64 + lane], acc1);
        acc1 = fmaf(b, sWn[k * 128 + 64 + lane], acc1);
    }

    float ss = acc0 * acc0 + acc1 * acc1;
#pragma unroll
    for (int off = 32; off; off >>= 1) ss += __shfl_xor(ss, off);
    float inv = 1.0f / (sqrtf(ss) + EPSN);

    h1[n * 128 + lane]      = fmaxf(acc0 * inv, 0.0f);
    h1[n * 128 + 64 + lane] = fmaxf(acc1 * inv, 0.0f);
}

// ================= layer 1 fused: CSR-mean aggregate + GEMV + normalize + log_softmax =================
__global__ void __launch_bounds__(512)
layer1_fused(const float* __restrict__ h1,
             const int* __restrict__ row_ptr, const int* __restrict__ col,
             const float* __restrict__ Ws, const float* __restrict__ Wn,
             float* __restrict__ out, int N) {
    __shared__ float sWs[129 * DOUT];
    __shared__ float sWn[129 * DOUT];
    for (int i = threadIdx.x; i < 129 * DOUT; i += 512) {
        sWs[i] = Ws[i];
        sWn[i] = Wn[i];
    }
    __syncthreads();

    int n = (int)((blockIdx.x * blockDim.x + threadIdx.x) >> 6);
    if (n >= N) return;
    int lane = threadIdx.x & 63;

    int rs = row_ptr[n], re = row_ptr[n + 1];
    float s0a = 0.0f, s1a = 0.0f;
    for (int base = rs; base < re; base += 64) {
        int cnt = min(64, re - base);
        int e = 0;
        if (base + lane < re) e = col[base + lane];
        int j = 0;
        for (; j + 1 < cnt; j += 2) {
            int t0 = __shfl(e, j), t1 = __shfl(e, j + 1);
            float u0 = h1[t0 * 128 + lane],      u1 = h1[t1 * 128 + lane];
            float w0 = h1[t0 * 128 + 64 + lane], w1 = h1[t1 * 128 + 64 + lane];
            s0a += u0; s0a += u1;
            s1a += w0; s1a += w1;
        }
        for (; j < cnt; ++j) {
            int t0 = __shfl(e, j);
            s0a += h1[t0 * 128 + lane];
            s1a += h1[t0 * 128 + 64 + lane];
        }
    }

    float deg   = (float)(re - rs);
    float scale = 1.0f / fmaxf(deg, 1.0f);
    float a0 = h1[n * 128 + lane];
    float a1 = h1[n * 128 + 64 + lane];
    float b0 = s0a * scale;
    float b1 = s1a * scale;
    float bones = deg * scale;

    float p[DOUT];
#pragma unroll
    for (int j = 0; j < DOUT; ++j) {
        float v = a0 * sWs[lane * DOUT + j] + b0 * sWn[lane * DOUT + j];
        v = fmaf(a1, sWs[(lane + 64) * DOUT + j], v);
        v = fmaf(b1, sWn[(lane + 64) * DOUT + j], v);
        if (lane == 0) v += sWs[128 * DOUT + j] + bones * sWn[128 * DOUT + j];
        p[j] = v;
    }
#pragma unroll
    for (int j = 0; j < DOUT; ++j) {
#pragma unroll
        for (int off = 32; off; off >>= 1) p[j] += __shfl_xor(p[j], off);
    }

    float ss = 0.0f;
#pragma unroll
    for (int j = 0; j < DOUT; ++j) ss = fmaf(p[j], p[j], ss);
    float inv = 1.0f / (sqrtf(ss) + EPSN);

    float m = -INFINITY;
#pragma unroll
    for (int j = 0; j < DOUT; ++j) { p[j] *= inv; m = fmaxf(m, p[j]); }
    float se = 0.0f;
#pragma unroll
    for (int j = 0; j < DOUT; ++j) se += expf(p[j] - m);
    float ls = logf(se) + m;

    if (lane < DOUT) {
        float v = 0.0f;
#pragma unroll
        for (int j = 0; j < DOUT; ++j) if (lane == j) v = p[j] - ls;
        out[n * DOUT + lane] = v;
    }
}

extern "C" void kernel_launch(void* const* d_in, const int* in_sizes, int n_in,
                              void* d_out, int out_size, void* d_ws, size_t ws_size,
                              hipStream_t stream) {
    const float* x   = (const float*)d_in[0];
    const int*   ei  = (const int*)d_in[1];
    const float* Ws0 = (const float*)d_in[2];
    const float* Wn0 = (const float*)d_in[3];
    const float* Ws1 = (const float*)d_in[4];
    const float* Wn1 = (const float*)d_in[5];

    int N = in_sizes[0] / 64;
    int E = in_sizes[1] / 2;
    const int* src = ei;
    const int* dst = ei + E;

    char* ws = (char*)d_ws;
    float* h1      = (float*)ws;                                   // N*128 f32
    int*   deg     = (int*)(ws + (size_t)N * 128 * 4);             // N
    int*   row_ptr = deg + N;                                      // N+1
    int*   cursor  = row_ptr + N + 1;                              // N
    int*   col     = cursor + N;                                   // E
    float* outp    = (float*)d_out;

    int eb  = (E + 255) / 256;
    int nb8 = (N + 7) / 8;   // 8 waves (nodes) per 512-thread block

    hipMemsetAsync(deg, 0, (size_t)N * 4, stream);
    hist_kernel<<<eb, 256, 0, stream>>>(dst, deg, E);
    scan_kernel<<<1, 1024, 0, stream>>>(deg, row_ptr, cursor, N);
    fill_kernel<<<eb, 256, 0, stream>>>(src, dst, cursor, col, E);

    layer0_fused<<<nb8, 512, 0, stream>>>(x, row_ptr, col, Ws0, Wn0, h1, N);
    layer1_fused<<<nb8, 512, 0, stream>>>(h1, row_ptr, col, Ws1, Wn1, outp, N);
}

// Round 4
// 349.546 us; speedup vs baseline: 2.7845x; 1.4631x over previous
//
#include <hip/hip_runtime.h>
#include <hip/hip_bf16.h>
#include <math.h>

#define EPSN 1e-8f

typedef __attribute__((ext_vector_type(8))) short short8;
typedef __attribute__((ext_vector_type(4))) float f32x4;

static __device__ __forceinline__ unsigned short f2bf(float f) {
    union { float f; unsigned int u; } v; v.f = f;
    unsigned int u = v.u;
    return (unsigned short)((u + 0x7fffu + ((u >> 16) & 1u)) >> 16);  // RNE
}

// ================= CSR build =================
__global__ void hist_kernel(const int* __restrict__ dst, int* __restrict__ deg, int E) {
    int e = blockIdx.x * blockDim.x + threadIdx.x;
    if (e < E) atomicAdd(&deg[dst[e]], 1);
}

__global__ void scan_kernel(const int* __restrict__ deg, int* __restrict__ row_ptr,
                            int* __restrict__ cursor, int N) {
    __shared__ int sums[1024];
    int t = threadIdx.x;
    int CH = (N + 1023) >> 10;
    int base = t * CH;
    int local = 0;
    for (int i = 0; i < CH; ++i) { int idx = base + i; if (idx < N) local += deg[idx]; }
    sums[t] = local;
    __syncthreads();
    for (int off = 1; off < 1024; off <<= 1) {
        int v = 0;
        if (t >= off) v = sums[t - off];
        __syncthreads();
        if (t >= off) sums[t] += v;
        __syncthreads();
    }
    int run = (t == 0) ? 0 : sums[t - 1];
    for (int i = 0; i < CH; ++i) {
        int idx = base + i;
        if (idx < N) { row_ptr[idx] = run; cursor[idx] = run; run += deg[idx]; }
    }
    if (t == 1023) row_ptr[N] = sums[1023];
}

__global__ void fill_kernel(const int* __restrict__ src, const int* __restrict__ dst,
                            int* __restrict__ cursor, int* __restrict__ col, int E) {
    int e = blockIdx.x * blockDim.x + threadIdx.x;
    if (e < E) { int pos = atomicAdd(&cursor[dst[e]], 1); col[pos] = src[e]; }
}

// ================= weight prep: B0t [128n][160k] bf16, B1t [32c][128k] bf16, bias[20] f32 =================
__global__ void prep_kernel(const float* __restrict__ Ws0, const float* __restrict__ Wn0,
                            const float* __restrict__ Ws1, const float* __restrict__ Wn1,
                            unsigned short* __restrict__ B0t, unsigned short* __restrict__ B1t,
                            float* __restrict__ bias) {
    int t = blockIdx.x * blockDim.x + threadIdx.x;
    if (t < 128 * 160) {
        int n = t / 160, k = t % 160;
        float v = 0.f;
        if (k < 65) v = Ws0[k * 128 + n];
        else if (k < 130) v = Wn0[(k - 65) * 128 + n];
        B0t[n * 160 + k] = f2bf(v);
    }
    int u = t - 128 * 160;
    if (u >= 0 && u < 32 * 128) {
        int c = u / 128, k = u % 128;
        float v = 0.f;
        if (c < 10) v = Ws1[k * 10 + c];
        else if (c < 20) v = Wn1[k * 10 + (c - 10)];
        B1t[c * 128 + k] = f2bf(v);
    }
    int w = t - 128 * 160 - 32 * 128;
    if (w >= 0 && w < 20) bias[w] = (w < 10) ? Ws1[128 * 10 + w] : Wn1[128 * 10 + (w - 10)];
}

// ================= layer0 aggregate: A0[n] = [x(64) | 1 | neigh(64) | degflag | 0pad] bf16 =================
__global__ void agg0_kernel(const float* __restrict__ x,
                            const int* __restrict__ row_ptr, const int* __restrict__ col,
                            unsigned short* __restrict__ A0, int N) {
    int n = (int)((blockIdx.x * blockDim.x + threadIdx.x) >> 6);
    if (n >= N) return;
    int lane = threadIdx.x & 63;
    int rs = row_ptr[n], re = row_ptr[n + 1];
    float acc = 0.f;
    for (int base = rs; base < re; base += 64) {
        int cnt = min(64, re - base);
        int e = 0;
        if (base + lane < re) e = col[base + lane];
        int j = 0;
        for (; j + 3 < cnt; j += 4) {
            int s0 = __shfl(e, j), s1 = __shfl(e, j + 1);
            int s2 = __shfl(e, j + 2), s3 = __shfl(e, j + 3);
            float v0 = x[s0 * 64 + lane], v1 = x[s1 * 64 + lane];
            float v2 = x[s2 * 64 + lane], v3 = x[s3 * 64 + lane];
            acc += v0; acc += v1; acc += v2; acc += v3;
        }
        for (; j < cnt; ++j) { int s = __shfl(e, j); acc += x[s * 64 + lane]; }
    }
    float deg = (float)(re - rs);
    float scale = 1.0f / fmaxf(deg, 1.0f);
    unsigned short* row = A0 + (size_t)n * 160;
    row[lane]      = f2bf(x[n * 64 + lane]);
    row[65 + lane] = f2bf(acc * scale);
    if (lane == 0) row[64]  = f2bf(1.0f);
    if (lane == 1) row[129] = f2bf(deg * scale);         // deg/max(deg,1) = 1 or 0
    if (lane >= 2 && lane < 32) row[128 + lane] = 0;     // zero pad cols 130..159
}

// ================= GEMM0: h1 = relu(normalize(A0 @ B0)) — MFMA, single-stage LDS =================
__global__ void __launch_bounds__(256)
gemm0_kernel(const unsigned short* __restrict__ A0, const unsigned short* __restrict__ B0t,
             unsigned short* __restrict__ h1, int N) {
    __shared__ unsigned short As[64 * 168];    // 64 rows, K=160 pad 168
    __shared__ unsigned short Bs[128 * 168];   // 128 out-cols, K=160 pad 168
    int t = threadIdx.x, blk = blockIdx.x;
    for (int i = t; i < 128 * 20; i += 256) {
        int r = i / 20, c = i % 20;
        *(uint4*)(&Bs[r * 168 + c * 8]) = *(const uint4*)(&B0t[r * 160 + c * 8]);
    }
    for (int i = t; i < 64 * 20; i += 256) {
        int r = i / 20, c = i % 20;
        int gr = blk * 64 + r;
        uint4 v = {0, 0, 0, 0};
        if (gr < N) v = *(const uint4*)(&A0[(size_t)gr * 160 + c * 8]);
        *(uint4*)(&As[r * 168 + c * 8]) = v;
    }
    __syncthreads();

    int wave = t >> 6, lane = t & 63;
    int lo = lane & 15, hi = lane >> 4;
    f32x4 acc[8];
#pragma unroll
    for (int f = 0; f < 8; ++f) acc[f] = (f32x4){0.f, 0.f, 0.f, 0.f};

#pragma unroll
    for (int ks = 0; ks < 5; ++ks) {
        short8 a = *(const short8*)(&As[(wave * 16 + lo) * 168 + ks * 32 + hi * 8]);
#pragma unroll
        for (int f = 0; f < 8; ++f) {
            short8 b = *(const short8*)(&Bs[(f * 16 + lo) * 168 + ks * 32 + hi * 8]);
            acc[f] = __builtin_amdgcn_mfma_f32_16x16x32_bf16(a, b, acc[f], 0, 0, 0);
        }
    }
    // epilogue: per-row L2 norm (cols spread over lo-group), relu, bf16 store
#pragma unroll
    for (int j = 0; j < 4; ++j) {
        float s = 0.f;
#pragma unroll
        for (int f = 0; f < 8; ++f) s += acc[f][j] * acc[f][j];
#pragma unroll
        for (int m = 1; m < 16; m <<= 1) s += __shfl_xor(s, m);
        float inv = 1.0f / (sqrtf(s) + EPSN);
        int gr = blk * 64 + wave * 16 + hi * 4 + j;
        if (gr < N) {
#pragma unroll
            for (int f = 0; f < 8; ++f)
                h1[(size_t)gr * 128 + f * 16 + lo] = f2bf(fmaxf(acc[f][j] * inv, 0.f));
        }
    }
}

// ================= GEMM1: T = h1 @ [Ws1|Wn1](0:128) + bias — [N x 20] f32 =================
__global__ void __launch_bounds__(256)
gemm1_kernel(const unsigned short* __restrict__ h1, const unsigned short* __restrict__ B1t,
             const float* __restrict__ bias, float* __restrict__ T, int N) {
    __shared__ unsigned short As[128 * 136];   // 128 rows, K=128 pad 136
    __shared__ unsigned short Bs[32 * 136];
    int t = threadIdx.x, blk = blockIdx.x;
    for (int i = t; i < 32 * 16; i += 256) {
        int r = i / 16, c = i % 16;
        *(uint4*)(&Bs[r * 136 + c * 8]) = *(const uint4*)(&B1t[r * 128 + c * 8]);
    }
    for (int i = t; i < 128 * 16; i += 256) {
        int r = i / 16, c = i % 16;
        int gr = blk * 128 + r;
        uint4 v = {0, 0, 0, 0};
        if (gr < N) v = *(const uint4*)(&h1[(size_t)gr * 128 + c * 8]);
        *(uint4*)(&As[r * 136 + c * 8]) = v;
    }
    __syncthreads();

    int wave = t >> 6, lane = t & 63, lo = lane & 15, hi = lane >> 4;
    f32x4 acc[2][2];
#pragma unroll
    for (int m = 0; m < 2; ++m) { acc[m][0] = (f32x4){0,0,0,0}; acc[m][1] = (f32x4){0,0,0,0}; }

#pragma unroll
    for (int ks = 0; ks < 4; ++ks) {
        short8 b0 = *(const short8*)(&Bs[lo * 136 + ks * 32 + hi * 8]);
        short8 b1 = *(const short8*)(&Bs[(16 + lo) * 136 + ks * 32 + hi * 8]);
#pragma unroll
        for (int m = 0; m < 2; ++m) {
            short8 a = *(const short8*)(&As[(wave * 32 + m * 16 + lo) * 136 + ks * 32 + hi * 8]);
            acc[m][0] = __builtin_amdgcn_mfma_f32_16x16x32_bf16(a, b0, acc[m][0], 0, 0, 0);
            acc[m][1] = __builtin_amdgcn_mfma_f32_16x16x32_bf16(a, b1, acc[m][1], 0, 0, 0);
        }
    }
#pragma unroll
    for (int m = 0; m < 2; ++m)
#pragma unroll
        for (int j = 0; j < 4; ++j) {
            int gr = blk * 128 + wave * 32 + m * 16 + hi * 4 + j;
            if (gr < N) {
                T[(size_t)gr * 20 + lo] = acc[m][0][j] + bias[lo];
                if (lo < 4) T[(size_t)gr * 20 + 16 + lo] = acc[m][1][j] + bias[16 + lo];
            }
        }
}

// ================= final: out = log_softmax(normalize(S + meanGather(Q))) =================
__global__ void final_kernel(const float* __restrict__ T,
                             const int* __restrict__ row_ptr, const int* __restrict__ col,
                             float* __restrict__ out, int N) {
    int n = blockIdx.x * blockDim.x + threadIdx.x;
    if (n >= N) return;
    int rs = row_ptr[n], re = row_ptr[n + 1];
    float q[10];
#pragma unroll
    for (int j = 0; j < 10; ++j) q[j] = 0.f;
    int e = rs;
    for (; e + 1 < re; e += 2) {
        const float* r0 = &T[(size_t)col[e] * 20 + 10];
        const float* r1 = &T[(size_t)col[e + 1] * 20 + 10];
#pragma unroll
        for (int j = 0; j < 10; ++j) q[j] += r0[j];
#pragma unroll
        for (int j = 0; j < 10; ++j) q[j] += r1[j];
    }
    if (e < re) {
        const float* r0 = &T[(size_t)col[e] * 20 + 10];
#pragma unroll
        for (int j = 0; j < 10; ++j) q[j] += r0[j];
    }
    float deg = (float)(re - rs);
    float scale = 1.0f / fmaxf(deg, 1.0f);
    const float* S = &T[(size_t)n * 20];
    float p[10], ss = 0.f;
#pragma unroll
    for (int j = 0; j < 10; ++j) { p[j] = S[j] + q[j] * scale; ss = fmaf(p[j], p[j], ss); }
    float inv = 1.0f / (sqrtf(ss) + EPSN);
    float m = -INFINITY;
#pragma unroll
    for (int j = 0; j < 10; ++j) { p[j] *= inv; m = fmaxf(m, p[j]); }
    float se = 0.f;
#pragma unroll
    for (int j = 0; j < 10; ++j) se += expf(p[j] - m);
    float ls = logf(se) + m;
#pragma unroll
    for (int j = 0; j < 10; ++j) out[(size_t)n * 10 + j] = p[j] - ls;
}

extern "C" void kernel_launch(void* const* d_in, const int* in_sizes, int n_in,
                              void* d_out, int out_size, void* d_ws, size_t ws_size,
                              hipStream_t stream) {
    const float* x   = (const float*)d_in[0];
    const int*   ei  = (const int*)d_in[1];
    const float* Ws0 = (const float*)d_in[2];
    const float* Wn0 = (const float*)d_in[3];
    const float* Ws1 = (const float*)d_in[4];
    const float* Wn1 = (const float*)d_in[5];

    int N = in_sizes[0] / 64;
    int E = in_sizes[1] / 2;
    const int* src = ei;
    const int* dst = ei + E;

    char* ws = (char*)d_ws;
    size_t off = 0;
    unsigned short* A0   = (unsigned short*)(ws + off); off += (size_t)N * 160 * 2;  // 16.0 MB
    unsigned short* h1   = (unsigned short*)(ws + off); off += (size_t)N * 128 * 2;  // 12.8 MB
    float*          T    = (float*)(ws + off);          off += (size_t)N * 20 * 4;   //  4.0 MB
    unsigned short* B0t  = (unsigned short*)(ws + off); off += 128 * 160 * 2;
    unsigned short* B1t  = (unsigned short*)(ws + off); off += 32 * 128 * 2;
    float*          bias = (float*)(ws + off);          off += 128;
    int*            deg  = (int*)(ws + off);            off += (size_t)N * 4;
    int*            rowp = (int*)(ws + off);            off += ((size_t)N + 4) * 4;
    int*            curs = (int*)(ws + off);            off += (size_t)N * 4;
    int*            colb = (int*)(ws + off);            off += (size_t)E * 4;
    float* outp = (float*)d_out;

    int eb = (E + 255) / 256;

    hipMemsetAsync(deg, 0, (size_t)N * 4, stream);
    hist_kernel<<<eb, 256, 0, stream>>>(dst, deg, E);
    scan_kernel<<<1, 1024, 0, stream>>>(deg, rowp, curs, N);
    fill_kernel<<<eb, 256, 0, stream>>>(src, dst, curs, colb, E);

    int pt = 128 * 160 + 32 * 128 + 20;
    prep_kernel<<<(pt + 255) / 256, 256, 0, stream>>>(Ws0, Wn0, Ws1, Wn1, B0t, B1t, bias);

    agg0_kernel<<<(N + 3) / 4, 256, 0, stream>>>(x, rowp, colb, A0, N);
    gemm0_kernel<<<(N + 63) / 64, 256, 0, stream>>>(A0, B0t, h1, N);
    gemm1_kernel<<<(N + 127) / 128, 256, 0, stream>>>(h1, B1t, bias, T, N);
    final_kernel<<<(N + 255) / 256, 256, 0, stream>>>(T, rowp, colb, outp, N);
}

// Round 5
// 243.369 us; speedup vs baseline: 3.9993x; 1.4363x over previous
//
#include <hip/hip_runtime.h>
#include <hip/hip_bf16.h>
#include <math.h>

#define EPSN 1e-8f
#define SCAN_CHUNK 2048   // elements per scan block (256 thr x 8)

typedef __attribute__((ext_vector_type(8))) short short8;
typedef __attribute__((ext_vector_type(4))) float f32x4;

static __device__ __forceinline__ unsigned short f2bf(float f) {
    union { float f; unsigned int u; } v; v.f = f;
    unsigned int u = v.u;
    return (unsigned short)((u + 0x7fffu + ((u >> 16) & 1u)) >> 16);  // RNE
}

// ================= CSR build =================
__global__ void hist_kernel(const int* __restrict__ dst, int* __restrict__ deg, int E) {
    int e = blockIdx.x * blockDim.x + threadIdx.x;
    if (e < E) atomicAdd(&deg[dst[e]], 1);
}

// phase A: per-block sums
__global__ void scan_partial(const int* __restrict__ deg, int* __restrict__ bsum, int N) {
    __shared__ int red[4];
    int base = blockIdx.x * SCAN_CHUNK + threadIdx.x * 8;
    int s = 0;
#pragma unroll
    for (int i = 0; i < 8; ++i) { int idx = base + i; if (idx < N) s += deg[idx]; }
#pragma unroll
    for (int off = 32; off; off >>= 1) s += __shfl_down(s, off);
    int wave = threadIdx.x >> 6, lane = threadIdx.x & 63;
    if (lane == 0) red[wave] = s;
    __syncthreads();
    if (threadIdx.x == 0) bsum[blockIdx.x] = red[0] + red[1] + red[2] + red[3];
}

// phase B: exclusive scan of block sums (single wave, chunks of 64)
__global__ void scan_bsums(const int* __restrict__ bsum, int* __restrict__ boff,
                           int nb, int* __restrict__ row_ptr, int N) {
    int t = threadIdx.x;  // 64 threads
    int carry = 0;
    for (int base = 0; base < nb; base += 64) {
        int v = (base + t < nb) ? bsum[base + t] : 0;
        int inc = v;
#pragma unroll
        for (int off = 1; off < 64; off <<= 1) {
            int y = __shfl_up(inc, off);
            if (t >= off) inc += y;
        }
        if (base + t < nb) boff[base + t] = carry + inc - v;
        carry += __shfl(inc, 63);
    }
    if (t == 0) row_ptr[N] = carry;
}

// phase C: per-block exclusive scan + global offset -> row_ptr, cursor
__global__ void scan_final(const int* __restrict__ deg, const int* __restrict__ boff,
                           int* __restrict__ row_ptr, int* __restrict__ cursor, int N) {
    __shared__ int woffs[4];
    int base = blockIdx.x * SCAN_CHUNK + threadIdx.x * 8;
    int v[8];
    int s = 0;
#pragma unroll
    for (int i = 0; i < 8; ++i) { int idx = base + i; v[i] = (idx < N) ? deg[idx] : 0; s += v[i]; }
    int lane = threadIdx.x & 63, wave = threadIdx.x >> 6;
    int inc = s;
#pragma unroll
    for (int off = 1; off < 64; off <<= 1) {
        int y = __shfl_up(inc, off);
        if (lane >= off) inc += y;
    }
    if (lane == 63) woffs[wave] = inc;
    __syncthreads();
    int woff = 0;
    for (int w = 0; w < wave; ++w) woff += woffs[w];
    int run = boff[blockIdx.x] + woff + (inc - s);
#pragma unroll
    for (int i = 0; i < 8; ++i) {
        int idx = base + i;
        if (idx < N) { row_ptr[idx] = run; cursor[idx] = run; run += v[i]; }
    }
}

__global__ void fill_kernel(const int* __restrict__ src, const int* __restrict__ dst,
                            int* __restrict__ cursor, int* __restrict__ col, int E) {
    int e = blockIdx.x * blockDim.x + threadIdx.x;
    if (e < E) { int pos = atomicAdd(&cursor[dst[e]], 1); col[pos] = src[e]; }
}

// ================= weight prep: B0t [128n][160k] bf16, B1t [32c][128k] bf16, bias[20] f32 =================
__global__ void prep_kernel(const float* __restrict__ Ws0, const float* __restrict__ Wn0,
                            const float* __restrict__ Ws1, const float* __restrict__ Wn1,
                            unsigned short* __restrict__ B0t, unsigned short* __restrict__ B1t,
                            float* __restrict__ bias) {
    int t = blockIdx.x * blockDim.x + threadIdx.x;
    if (t < 128 * 160) {
        int n = t / 160, k = t % 160;
        float v = 0.f;
        if (k < 65) v = Ws0[k * 128 + n];
        else if (k < 130) v = Wn0[(k - 65) * 128 + n];
        B0t[n * 160 + k] = f2bf(v);
    }
    int u = t - 128 * 160;
    if (u >= 0 && u < 32 * 128) {
        int c = u / 128, k = u % 128;
        float v = 0.f;
        if (c < 10) v = Ws1[k * 10 + c];
        else if (c < 20) v = Wn1[k * 10 + (c - 10)];
        B1t[c * 128 + k] = f2bf(v);
    }
    int w = t - 128 * 160 - 32 * 128;
    if (w >= 0 && w < 20) bias[w] = (w < 10) ? Ws1[128 * 10 + w] : Wn1[128 * 10 + (w - 10)];
}

// ================= layer0 aggregate: A0[n] = [x(64) | 1 | neigh(64) | degflag | 0pad] bf16 =================
__global__ void agg0_kernel(const float* __restrict__ x,
                            const int* __restrict__ row_ptr, const int* __restrict__ col,
                            unsigned short* __restrict__ A0, int N) {
    int n = (int)((blockIdx.x * blockDim.x + threadIdx.x) >> 6);
    if (n >= N) return;
    int lane = threadIdx.x & 63;
    int rs = row_ptr[n], re = row_ptr[n + 1];
    float acc = 0.f;
    for (int base = rs; base < re; base += 64) {
        int cnt = min(64, re - base);
        int e = 0;
        if (base + lane < re) e = col[base + lane];
        int j = 0;
        for (; j + 3 < cnt; j += 4) {
            int s0 = __shfl(e, j), s1 = __shfl(e, j + 1);
            int s2 = __shfl(e, j + 2), s3 = __shfl(e, j + 3);
            float v0 = x[s0 * 64 + lane], v1 = x[s1 * 64 + lane];
            float v2 = x[s2 * 64 + lane], v3 = x[s3 * 64 + lane];
            acc += v0; acc += v1; acc += v2; acc += v3;
        }
        for (; j < cnt; ++j) { int s = __shfl(e, j); acc += x[s * 64 + lane]; }
    }
    float deg = (float)(re - rs);
    float scale = 1.0f / fmaxf(deg, 1.0f);
    unsigned short* row = A0 + (size_t)n * 160;
    row[lane]      = f2bf(x[n * 64 + lane]);
    row[65 + lane] = f2bf(acc * scale);
    if (lane == 0) row[64]  = f2bf(1.0f);
    if (lane == 1) row[129] = f2bf(deg * scale);         // deg/max(deg,1) = 1 or 0
    if (lane >= 2 && lane < 32) row[128 + lane] = 0;     // zero pad cols 130..159
}

// ================= GEMM0: h1 = relu(normalize(A0 @ B0)) — MFMA, single-stage LDS =================
__global__ void __launch_bounds__(256)
gemm0_kernel(const unsigned short* __restrict__ A0, const unsigned short* __restrict__ B0t,
             unsigned short* __restrict__ h1, int N) {
    __shared__ unsigned short As[64 * 168];    // 64 rows, K=160 pad 168
    __shared__ unsigned short Bs[128 * 168];   // 128 out-cols, K=160 pad 168
    int t = threadIdx.x, blk = blockIdx.x;
    for (int i = t; i < 128 * 20; i += 256) {
        int r = i / 20, c = i % 20;
        *(uint4*)(&Bs[r * 168 + c * 8]) = *(const uint4*)(&B0t[r * 160 + c * 8]);
    }
    for (int i = t; i < 64 * 20; i += 256) {
        int r = i / 20, c = i % 20;
        int gr = blk * 64 + r;
        uint4 v = {0, 0, 0, 0};
        if (gr < N) v = *(const uint4*)(&A0[(size_t)gr * 160 + c * 8]);
        *(uint4*)(&As[r * 168 + c * 8]) = v;
    }
    __syncthreads();

    int wave = t >> 6, lane = t & 63;
    int lo = lane & 15, hi = lane >> 4;
    f32x4 acc[8];
#pragma unroll
    for (int f = 0; f < 8; ++f) acc[f] = (f32x4){0.f, 0.f, 0.f, 0.f};

#pragma unroll
    for (int ks = 0; ks < 5; ++ks) {
        short8 a = *(const short8*)(&As[(wave * 16 + lo) * 168 + ks * 32 + hi * 8]);
#pragma unroll
        for (int f = 0; f < 8; ++f) {
            short8 b = *(const short8*)(&Bs[(f * 16 + lo) * 168 + ks * 32 + hi * 8]);
            acc[f] = __builtin_amdgcn_mfma_f32_16x16x32_bf16(a, b, acc[f], 0, 0, 0);
        }
    }
    // epilogue: per-row L2 norm (cols spread over lo-group), relu, bf16 store
#pragma unroll
    for (int j = 0; j < 4; ++j) {
        float s = 0.f;
#pragma unroll
        for (int f = 0; f < 8; ++f) s += acc[f][j] * acc[f][j];
#pragma unroll
        for (int m = 1; m < 16; m <<= 1) s += __shfl_xor(s, m);
        float inv = 1.0f / (sqrtf(s) + EPSN);
        int gr = blk * 64 + wave * 16 + hi * 4 + j;
        if (gr < N) {
#pragma unroll
            for (int f = 0; f < 8; ++f)
                h1[(size_t)gr * 128 + f * 16 + lo] = f2bf(fmaxf(acc[f][j] * inv, 0.f));
        }
    }
}

// ================= GEMM1: T = h1 @ [Ws1|Wn1](0:128) + bias — [N x 20] f32 =================
__global__ void __launch_bounds__(256)
gemm1_kernel(const unsigned short* __restrict__ h1, const unsigned short* __restrict__ B1t,
             const float* __restrict__ bias, float* __restrict__ T, int N) {
    __shared__ unsigned short As[128 * 136];   // 128 rows, K=128 pad 136
    __shared__ unsigned short Bs[32 * 136];
    int t = threadIdx.x, blk = blockIdx.x;
    for (int i = t; i < 32 * 16; i += 256) {
        int r = i / 16, c = i % 16;
        *(uint4*)(&Bs[r * 136 + c * 8]) = *(const uint4*)(&B1t[r * 128 + c * 8]);
    }
    for (int i = t; i < 128 * 16; i += 256) {
        int r = i / 16, c = i % 16;
        int gr = blk * 128 + r;
        uint4 v = {0, 0, 0, 0};
        if (gr < N) v = *(const uint4*)(&h1[(size_t)gr * 128 + c * 8]);
        *(uint4*)(&As[r * 136 + c * 8]) = v;
    }
    __syncthreads();

    int wave = t >> 6, lane = t & 63, lo = lane & 15, hi = lane >> 4;
    f32x4 acc[2][2];
#pragma unroll
    for (int m = 0; m < 2; ++m) { acc[m][0] = (f32x4){0,0,0,0}; acc[m][1] = (f32x4){0,0,0,0}; }

#pragma unroll
    for (int ks = 0; ks < 4; ++ks) {
        short8 b0 = *(const short8*)(&Bs[lo * 136 + ks * 32 + hi * 8]);
        short8 b1 = *(const short8*)(&Bs[(16 + lo) * 136 + ks * 32 + hi * 8]);
#pragma unroll
        for (int m = 0; m < 2; ++m) {
            short8 a = *(const short8*)(&As[(wave * 32 + m * 16 + lo) * 136 + ks * 32 + hi * 8]);
            acc[m][0] = __builtin_amdgcn_mfma_f32_16x16x32_bf16(a, b0, acc[m][0], 0, 0, 0);
            acc[m][1] = __builtin_amdgcn_mfma_f32_16x16x32_bf16(a, b1, acc[m][1], 0, 0, 0);
        }
    }
#pragma unroll
    for (int m = 0; m < 2; ++m)
#pragma unroll
        for (int j = 0; j < 4; ++j) {
            int gr = blk * 128 + wave * 32 + m * 16 + hi * 4 + j;
            if (gr < N) {
                T[(size_t)gr * 20 + lo] = acc[m][0][j] + bias[lo];
                if (lo < 4) T[(size_t)gr * 20 + 16 + lo] = acc[m][1][j] + bias[16 + lo];
            }
        }
}

// ================= final: out = log_softmax(normalize(S + meanGather(Q))) =================
__global__ void final_kernel(const float* __restrict__ T,
                             const int* __restrict__ row_ptr, const int* __restrict__ col,
                             float* __restrict__ out, int N) {
    int n = blockIdx.x * blockDim.x + threadIdx.x;
    if (n >= N) return;
    int rs = row_ptr[n], re = row_ptr[n + 1];
    float q[10];
#pragma unroll
    for (int j = 0; j < 10; ++j) q[j] = 0.f;
    int e = rs;
    for (; e + 1 < re; e += 2) {
        const float* r0 = &T[(size_t)col[e] * 20 + 10];
        const float* r1 = &T[(size_t)col[e + 1] * 20 + 10];
#pragma unroll
        for (int j = 0; j < 10; ++j) q[j] += r0[j];
#pragma unroll
        for (int j = 0; j < 10; ++j) q[j] += r1[j];
    }
    if (e < re) {
        const float* r0 = &T[(size_t)col[e] * 20 + 10];
#pragma unroll
        for (int j = 0; j < 10; ++j) q[j] += r0[j];
    }
    float deg = (float)(re - rs);
    float scale = 1.0f / fmaxf(deg, 1.0f);
    const float* S = &T[(size_t)n * 20];
    float p[10], ss = 0.f;
#pragma unroll
    for (int j = 0; j < 10; ++j) { p[j] = S[j] + q[j] * scale; ss = fmaf(p[j], p[j], ss); }
    float inv = 1.0f / (sqrtf(ss) + EPSN);
    float m = -INFINITY;
#pragma unroll
    for (int j = 0; j < 10; ++j) { p[j] *= inv; m = fmaxf(m, p[j]); }
    float se = 0.f;
#pragma unroll
    for (int j = 0; j < 10; ++j) se += expf(p[j] - m);
    float ls = logf(se) + m;
#pragma unroll
    for (int j = 0; j < 10; ++j) out[(size_t)n * 10 + j] = p[j] - ls;
}

extern "C" void kernel_launch(void* const* d_in, const int* in_sizes, int n_in,
                              void* d_out, int out_size, void* d_ws, size_t ws_size,
                              hipStream_t stream) {
    const float* x   = (const float*)d_in[0];
    const int*   ei  = (const int*)d_in[1];
    const float* Ws0 = (const float*)d_in[2];
    const float* Wn0 = (const float*)d_in[3];
    const float* Ws1 = (const float*)d_in[4];
    const float* Wn1 = (const float*)d_in[5];

    int N = in_sizes[0] / 64;
    int E = in_sizes[1] / 2;
    const int* src = ei;
    const int* dst = ei + E;

    char* ws = (char*)d_ws;
    size_t off = 0;
    unsigned short* A0   = (unsigned short*)(ws + off); off += (size_t)N * 160 * 2;  // 16.0 MB
    unsigned short* h1   = (unsigned short*)(ws + off); off += (size_t)N * 128 * 2;  // 12.8 MB
    float*          T    = (float*)(ws + off);          off += (size_t)N * 20 * 4;   //  4.0 MB
    unsigned short* B0t  = (unsigned short*)(ws + off); off += 128 * 160 * 2;
    unsigned short* B1t  = (unsigned short*)(ws + off); off += 32 * 128 * 2;
    float*          bias = (float*)(ws + off);          off += 128;
    int*            deg  = (int*)(ws + off);            off += (size_t)N * 4;
    int*            rowp = (int*)(ws + off);            off += ((size_t)N + 4) * 4;
    int*            curs = (int*)(ws + off);            off += (size_t)N * 4;
    int*            colb = (int*)(ws + off);            off += (size_t)E * 4;
    int*            bsum = (int*)(ws + off);            off += 1024;
    int*            boff = (int*)(ws + off);            off += 1024;
    float* outp = (float*)d_out;

    int eb = (E + 255) / 256;
    int nb = (N + SCAN_CHUNK - 1) / SCAN_CHUNK;

    hipMemsetAsync(deg, 0, (size_t)N * 4, stream);
    hist_kernel<<<eb, 256, 0, stream>>>(dst, deg, E);
    scan_partial<<<nb, 256, 0, stream>>>(deg, bsum, N);
    scan_bsums<<<1, 64, 0, stream>>>(bsum, boff, nb, rowp, N);
    scan_final<<<nb, 256, 0, stream>>>(deg, boff, rowp, curs, N);
    fill_kernel<<<eb, 256, 0, stream>>>(src, dst, curs, colb, E);

    int pt = 128 * 160 + 32 * 128 + 20;
    prep_kernel<<<(pt + 255) / 256, 256, 0, stream>>>(Ws0, Wn0, Ws1, Wn1, B0t, B1t, bias);

    agg0_kernel<<<(N + 3) / 4, 256, 0, stream>>>(x, rowp, colb, A0, N);
    gemm0_kernel<<<(N + 63) / 64, 256, 0, stream>>>(A0, B0t, h1, N);
    gemm1_kernel<<<(N + 127) / 128, 256, 0, stream>>>(h1, B1t, bias, T, N);
    final_kernel<<<(N + 255) / 256, 256, 0, stream>>>(T, rowp, colb, outp, N);
}

// Round 6
// 180.556 us; speedup vs baseline: 5.3906x; 1.3479x over previous
//
#include <hip/hip_runtime.h>
#include <hip/hip_bf16.h>
#include <math.h>

#define EPSN 1e-8f
#define MAXBUCK 512          // buckets of 128 nodes; N must be < 65536 (ushort col)

typedef __attribute__((ext_vector_type(8))) short short8;
typedef __attribute__((ext_vector_type(4))) float f32x4;

static __device__ __forceinline__ unsigned short f2bf(float f) {
    union { float f; unsigned int u; } v; v.f = f;
    unsigned int u = v.u;
    return (unsigned short)((u + 0x7fffu + ((u >> 16) & 1u)) >> 16);  // RNE
}
static __device__ __forceinline__ float bf2f(unsigned short h) {
    union { unsigned int u; float f; } v; v.u = ((unsigned int)h) << 16;
    return v.f;
}

// ================= CSR build (binned counting sort) =================
// k1: global bucket histogram via per-block LDS hist
__global__ void bucket_hist(const int* __restrict__ dst, int* __restrict__ ghist,
                            int E, int nbuck) {
    __shared__ int h[MAXBUCK];
    for (int i = threadIdx.x; i < MAXBUCK; i += 256) h[i] = 0;
    __syncthreads();
    int CH = (E + gridDim.x - 1) / gridDim.x;
    int lo = blockIdx.x * CH, hi = min(E, lo + CH);
    for (int e = lo + (int)threadIdx.x; e < hi; e += 256) atomicAdd(&h[dst[e] >> 7], 1);
    __syncthreads();
    for (int i = threadIdx.x; i < nbuck; i += 256) if (h[i]) atomicAdd(&ghist[i], h[i]);
}

// k2: 1-block scan of bucket counts -> boff[nbuck+1], bcur; row_ptr[N]=E
__global__ void bucket_scan(const int* __restrict__ ghist, int* __restrict__ boff,
                            int* __restrict__ bcur, int nbuck, int E,
                            int* __restrict__ row_ptr, int N) {
    __shared__ int bufa[MAXBUCK], bufb[MAXBUCK];
    int t = threadIdx.x;  // 512 threads
    int v = (t < nbuck) ? ghist[t] : 0;
    bufa[t] = v;
    __syncthreads();
    int* cur = bufa; int* nxt = bufb;
    for (int off = 1; off < MAXBUCK; off <<= 1) {
        int x = cur[t];
        if (t >= off) x += cur[t - off];
        nxt[t] = x;
        __syncthreads();
        int* tmp = cur; cur = nxt; nxt = tmp;
    }
    int incl = cur[t];
    int excl = incl - v;
    if (t < nbuck) { boff[t] = excl; bcur[t] = excl; }
    if (t == nbuck - 1) boff[nbuck] = incl;   // == E
    if (t == 0) row_ptr[N] = E;
}

// k3: binned scatter of packed (local_dst<<16 | src) with per-block chunk reservation
__global__ void bucket_scatter(const int* __restrict__ src, const int* __restrict__ dst,
                               int* __restrict__ bcur, unsigned int* __restrict__ pairs,
                               int E) {
    __shared__ int h[MAXBUCK];
    __shared__ int bs[MAXBUCK];
    for (int i = threadIdx.x; i < MAXBUCK; i += 256) h[i] = 0;
    __syncthreads();
    int CH = (E + gridDim.x - 1) / gridDim.x;
    int lo = blockIdx.x * CH, hi = min(E, lo + CH);
    for (int e = lo + (int)threadIdx.x; e < hi; e += 256) atomicAdd(&h[dst[e] >> 7], 1);
    __syncthreads();
    for (int i = threadIdx.x; i < MAXBUCK; i += 256) {
        int c = h[i];
        bs[i] = c ? atomicAdd(&bcur[i], c) : 0;
        h[i] = 0;
    }
    __syncthreads();
    for (int e = lo + (int)threadIdx.x; e < hi; e += 256) {
        int d = dst[e];
        int b = d >> 7;
        int idx = atomicAdd(&h[b], 1);
        pairs[bs[b] + idx] = (((unsigned int)(d & 127)) << 16) | (unsigned int)src[e];
    }
}

// k4: per-bucket finalize -> row_ptr + ushort col
__global__ void csr_finalize(const unsigned int* __restrict__ pairs, const int* __restrict__ boff,
                             int* __restrict__ row_ptr, unsigned short* __restrict__ col,
                             int N) {
    __shared__ int lh[128], ls[128], lc[128];
    int b = blockIdx.x, t = threadIdx.x;  // 256 threads
    int lo = boff[b], hi = boff[b + 1];
    for (int i = t; i < 128; i += 256) lh[i] = 0;
    __syncthreads();
    for (int e = lo + t; e < hi; e += 256) atomicAdd(&lh[pairs[e] >> 16], 1);
    __syncthreads();
    if (t < 128) {
        int v = lh[t];
        int incl = v;
#pragma unroll
        for (int off = 1; off < 64; off <<= 1) {
            int y = __shfl_up(incl, off);
            if ((t & 63) >= off) incl += y;
        }
        ls[t] = incl;
    }
    __syncthreads();
    if (t < 128) {
        int v = lh[t];
        int excl = ls[t] - v + ((t >= 64) ? ls[63] : 0);
        int node = b * 128 + t;
        if (node < N) row_ptr[node] = lo + excl;
        lc[t] = excl;
    }
    __syncthreads();
    for (int e = lo + t; e < hi; e += 256) {
        unsigned int p = pairs[e];
        int ld = p >> 16;
        int idx = atomicAdd(&lc[ld], 1);
        col[lo + idx] = (unsigned short)(p & 0xFFFFu);
    }
}

// ================= weight prep =================
__global__ void prep_kernel(const float* __restrict__ Ws0, const float* __restrict__ Wn0,
                            const float* __restrict__ Ws1, const float* __restrict__ Wn1,
                            unsigned short* __restrict__ B0t, unsigned short* __restrict__ B1t,
                            float* __restrict__ bias) {
    int t = blockIdx.x * blockDim.x + threadIdx.x;
    if (t < 128 * 160) {
        int n = t / 160, k = t % 160;
        float v = 0.f;
        if (k < 65) v = Ws0[k * 128 + n];
        else if (k < 130) v = Wn0[(k - 65) * 128 + n];
        B0t[n * 160 + k] = f2bf(v);
    }
    int u = t - 128 * 160;
    if (u >= 0 && u < 32 * 128) {
        int c = u / 128, k = u % 128;
        float v = 0.f;
        if (c < 10) v = Ws1[k * 10 + c];
        else if (c < 20) v = Wn1[k * 10 + (c - 10)];
        B1t[c * 128 + k] = f2bf(v);
    }
    int w = t - 128 * 160 - 32 * 128;
    if (w >= 0 && w < 20) bias[w] = (w < 10) ? Ws1[128 * 10 + w] : Wn1[128 * 10 + (w - 10)];
}

// ================= xconv: A0[n][0..63] = bf16(x[n]) =================
__global__ void xconv_kernel(const float* __restrict__ x, unsigned short* __restrict__ A0, int N) {
    int u = blockIdx.x * blockDim.x + threadIdx.x;   // u = n*8 + s
    if (u >= N * 8) return;
    int n = u >> 3, s = u & 7;
    const float4* xp = (const float4*)(x + (size_t)n * 64 + s * 8);
    float4 v0 = xp[0], v1 = xp[1];
    short8 r;
    r[0] = (short)f2bf(v0.x); r[1] = (short)f2bf(v0.y);
    r[2] = (short)f2bf(v0.z); r[3] = (short)f2bf(v0.w);
    r[4] = (short)f2bf(v1.x); r[5] = (short)f2bf(v1.y);
    r[6] = (short)f2bf(v1.z); r[7] = (short)f2bf(v1.w);
    *(short8*)(&A0[(size_t)n * 160 + s * 8]) = r;
}

// ================= agg0: gather-mean of bf16 x rows -> A0 cols 64..159 =================
__global__ void agg0_kernel(const int* __restrict__ row_ptr, const unsigned short* __restrict__ col,
                            unsigned short* __restrict__ A0, int N) {
    int n = (int)((blockIdx.x * blockDim.x + threadIdx.x) >> 6);
    if (n >= N) return;
    int lane = threadIdx.x & 63;
    int rs = row_ptr[n], re = row_ptr[n + 1];
    float acc = 0.f;
    for (int base = rs; base < re; base += 64) {
        int cnt = min(64, re - base);
        int e = 0;
        if (base + lane < re) e = (int)col[base + lane];
        int j = 0;
        for (; j + 3 < cnt; j += 4) {
            int s0 = __shfl(e, j), s1 = __shfl(e, j + 1);
            int s2 = __shfl(e, j + 2), s3 = __shfl(e, j + 3);
            float v0 = bf2f(A0[(size_t)s0 * 160 + lane]);
            float v1 = bf2f(A0[(size_t)s1 * 160 + lane]);
            float v2 = bf2f(A0[(size_t)s2 * 160 + lane]);
            float v3 = bf2f(A0[(size_t)s3 * 160 + lane]);
            acc += v0; acc += v1; acc += v2; acc += v3;
        }
        for (; j < cnt; ++j) {
            int s = __shfl(e, j);
            acc += bf2f(A0[(size_t)s * 160 + lane]);
        }
    }
    float deg = (float)(re - rs);
    float scale = 1.0f / fmaxf(deg, 1.0f);
    unsigned short* row = A0 + (size_t)n * 160;
    row[65 + lane] = f2bf(acc * scale);
    if (lane == 0) row[64]  = 0x3F80;                 // 1.0 bf16
    if (lane == 1) row[129] = f2bf(deg * scale);      // mean of ones
    if (lane >= 2 && lane < 32) row[128 + lane] = 0;  // zero pad 130..159
}

// ================= GEMM0: h1 = relu(normalize(A0 @ B0)) =================
__global__ void __launch_bounds__(256)
gemm0_kernel(const unsigned short* __restrict__ A0, const unsigned short* __restrict__ B0t,
             unsigned short* __restrict__ h1, int N) {
    __shared__ unsigned short As[64 * 168];
    __shared__ unsigned short Bs[128 * 168];
    int t = threadIdx.x, blk = blockIdx.x;
    for (int i = t; i < 128 * 20; i += 256) {
        int r = i / 20, c = i % 20;
        *(uint4*)(&Bs[r * 168 + c * 8]) = *(const uint4*)(&B0t[r * 160 + c * 8]);
    }
    for (int i = t; i < 64 * 20; i += 256) {
        int r = i / 20, c = i % 20;
        int gr = blk * 64 + r;
        uint4 v = {0, 0, 0, 0};
        if (gr < N) v = *(const uint4*)(&A0[(size_t)gr * 160 + c * 8]);
        *(uint4*)(&As[r * 168 + c * 8]) = v;
    }
    __syncthreads();

    int wave = t >> 6, lane = t & 63;
    int lo = lane & 15, hi = lane >> 4;
    f32x4 acc[8];
#pragma unroll
    for (int f = 0; f < 8; ++f) acc[f] = (f32x4){0.f, 0.f, 0.f, 0.f};

#pragma unroll
    for (int ks = 0; ks < 5; ++ks) {
        short8 a = *(const short8*)(&As[(wave * 16 + lo) * 168 + ks * 32 + hi * 8]);
#pragma unroll
        for (int f = 0; f < 8; ++f) {
            short8 b = *(const short8*)(&Bs[(f * 16 + lo) * 168 + ks * 32 + hi * 8]);
            acc[f] = __builtin_amdgcn_mfma_f32_16x16x32_bf16(a, b, acc[f], 0, 0, 0);
        }
    }
#pragma unroll
    for (int j = 0; j < 4; ++j) {
        float s = 0.f;
#pragma unroll
        for (int f = 0; f < 8; ++f) s += acc[f][j] * acc[f][j];
#pragma unroll
        for (int m = 1; m < 16; m <<= 1) s += __shfl_xor(s, m);
        float inv = 1.0f / (sqrtf(s) + EPSN);
        int gr = blk * 64 + wave * 16 + hi * 4 + j;
        if (gr < N) {
#pragma unroll
            for (int f = 0; f < 8; ++f)
                h1[(size_t)gr * 128 + f * 16 + lo] = f2bf(fmaxf(acc[f][j] * inv, 0.f));
        }
    }
}

// ================= GEMM1: S = h1@Ws1+b (cols 0..9), Q = h1@Wn1+b (cols 10..19) =================
__global__ void __launch_bounds__(256)
gemm1_kernel(const unsigned short* __restrict__ h1, const unsigned short* __restrict__ B1t,
             const float* __restrict__ bias, float* __restrict__ S, float* __restrict__ Q, int N) {
    __shared__ unsigned short As[128 * 136];
    __shared__ unsigned short Bs[32 * 136];
    int t = threadIdx.x, blk = blockIdx.x;
    for (int i = t; i < 32 * 16; i += 256) {
        int r = i / 16, c = i % 16;
        *(uint4*)(&Bs[r * 136 + c * 8]) = *(const uint4*)(&B1t[r * 128 + c * 8]);
    }
    for (int i = t; i < 128 * 16; i += 256) {
        int r = i / 16, c = i % 16;
        int gr = blk * 128 + r;
        uint4 v = {0, 0, 0, 0};
        if (gr < N) v = *(const uint4*)(&h1[(size_t)gr * 128 + c * 8]);
        *(uint4*)(&As[r * 136 + c * 8]) = v;
    }
    __syncthreads();

    int wave = t >> 6, lane = t & 63, lo = lane & 15, hi = lane >> 4;
    f32x4 acc[2][2];
#pragma unroll
    for (int m = 0; m < 2; ++m) { acc[m][0] = (f32x4){0,0,0,0}; acc[m][1] = (f32x4){0,0,0,0}; }

#pragma unroll
    for (int ks = 0; ks < 4; ++ks) {
        short8 b0 = *(const short8*)(&Bs[lo * 136 + ks * 32 + hi * 8]);
        short8 b1 = *(const short8*)(&Bs[(16 + lo) * 136 + ks * 32 + hi * 8]);
#pragma unroll
        for (int m = 0; m < 2; ++m) {
            short8 a = *(const short8*)(&As[(wave * 32 + m * 16 + lo) * 136 + ks * 32 + hi * 8]);
            acc[m][0] = __builtin_amdgcn_mfma_f32_16x16x32_bf16(a, b0, acc[m][0], 0, 0, 0);
            acc[m][1] = __builtin_amdgcn_mfma_f32_16x16x32_bf16(a, b1, acc[m][1], 0, 0, 0);
        }
    }
#pragma unroll
    for (int m = 0; m < 2; ++m)
#pragma unroll
        for (int j = 0; j < 4; ++j) {
            int gr = blk * 128 + wave * 32 + m * 16 + hi * 4 + j;
            if (gr < N) {
                float v0 = acc[m][0][j] + bias[lo];
                if (lo < 10) S[(size_t)gr * 10 + lo] = v0;
                else         Q[(size_t)gr * 10 + (lo - 10)] = v0;
                if (lo < 4)  Q[(size_t)gr * 10 + 6 + lo] = acc[m][1][j] + bias[16 + lo];
            }
        }
}

// ================= final: out = log_softmax(normalize(S + meanGather(Q))) =================
__global__ void final_kernel(const float* __restrict__ S, const float* __restrict__ Q,
                             const int* __restrict__ row_ptr, const unsigned short* __restrict__ col,
                             float* __restrict__ out, int N) {
    int n = blockIdx.x * blockDim.x + threadIdx.x;
    if (n >= N) return;
    int rs = row_ptr[n], re = row_ptr[n + 1];
    float q[10];
#pragma unroll
    for (int j = 0; j < 10; ++j) q[j] = 0.f;
    int e = rs;
    for (; e + 1 < re; e += 2) {
        const float* r0 = &Q[(size_t)col[e] * 10];
        const float* r1 = &Q[(size_t)col[e + 1] * 10];
#pragma unroll
        for (int j = 0; j < 10; ++j) q[j] += r0[j];
#pragma unroll
        for (int j = 0; j < 10; ++j) q[j] += r1[j];
    }
    if (e < re) {
        const float* r0 = &Q[(size_t)col[e] * 10];
#pragma unroll
        for (int j = 0; j < 10; ++j) q[j] += r0[j];
    }
    float deg = (float)(re - rs);
    float scale = 1.0f / fmaxf(deg, 1.0f);
    const float* Sr = &S[(size_t)n * 10];
    float p[10], ss = 0.f;
#pragma unroll
    for (int j = 0; j < 10; ++j) { p[j] = Sr[j] + q[j] * scale; ss = fmaf(p[j], p[j], ss); }
    float inv = 1.0f / (sqrtf(ss) + EPSN);
    float m = -INFINITY;
#pragma unroll
    for (int j = 0; j < 10; ++j) { p[j] *= inv; m = fmaxf(m, p[j]); }
    float se = 0.f;
#pragma unroll
    for (int j = 0; j < 10; ++j) se += expf(p[j] - m);
    float ls = logf(se) + m;
#pragma unroll
    for (int j = 0; j < 10; ++j) out[(size_t)n * 10 + j] = p[j] - ls;
}

extern "C" void kernel_launch(void* const* d_in, const int* in_sizes, int n_in,
                              void* d_out, int out_size, void* d_ws, size_t ws_size,
                              hipStream_t stream) {
    const float* x   = (const float*)d_in[0];
    const int*   ei  = (const int*)d_in[1];
    const float* Ws0 = (const float*)d_in[2];
    const float* Wn0 = (const float*)d_in[3];
    const float* Ws1 = (const float*)d_in[4];
    const float* Wn1 = (const float*)d_in[5];

    int N = in_sizes[0] / 64;
    int E = in_sizes[1] / 2;
    const int* src = ei;
    const int* dst = ei + E;
    int nbuck = (N + 127) / 128;

    char* ws = (char*)d_ws;
    size_t off = 0;
    unsigned short* A0   = (unsigned short*)(ws + off); off += (size_t)N * 160 * 2;
    unsigned short* h1   = (unsigned short*)(ws + off); off += (size_t)N * 128 * 2;
    float*          S    = (float*)(ws + off);          off += (size_t)N * 10 * 4;
    float*          Q    = (float*)(ws + off);          off += (size_t)N * 10 * 4;
    unsigned short* B0t  = (unsigned short*)(ws + off); off += 128 * 160 * 2;
    unsigned short* B1t  = (unsigned short*)(ws + off); off += 32 * 128 * 2;
    float*          bias = (float*)(ws + off);          off += 128;
    int*            rowp = (int*)(ws + off);            off += ((size_t)N + 4) * 4;
    unsigned short* colb = (unsigned short*)(ws + off); off += ((size_t)E + 8) * 2;
    unsigned int*   pairs= (unsigned int*)(ws + off);   off += (size_t)E * 4;
    int*            ghist= (int*)(ws + off);            off += MAXBUCK * 4;
    int*            boff = (int*)(ws + off);            off += (MAXBUCK + 1) * 4;
    int*            bcur = (int*)(ws + off);            off += MAXBUCK * 4;
    float* outp = (float*)d_out;

    hipMemsetAsync(ghist, 0, MAXBUCK * 4, stream);
    bucket_hist   <<<256, 256, 0, stream>>>(dst, ghist, E, nbuck);
    bucket_scan   <<<1, MAXBUCK, 0, stream>>>(ghist, boff, bcur, nbuck, E, rowp, N);
    bucket_scatter<<<256, 256, 0, stream>>>(src, dst, bcur, pairs, E);
    csr_finalize  <<<nbuck, 256, 0, stream>>>(pairs, boff, rowp, colb, N);

    int pt = 128 * 160 + 32 * 128 + 20;
    prep_kernel<<<(pt + 255) / 256, 256, 0, stream>>>(Ws0, Wn0, Ws1, Wn1, B0t, B1t, bias);

    xconv_kernel<<<(N * 8 + 255) / 256, 256, 0, stream>>>(x, A0, N);
    agg0_kernel <<<(N + 3) / 4, 256, 0, stream>>>(rowp, colb, A0, N);
    gemm0_kernel<<<(N + 63) / 64, 256, 0, stream>>>(A0, B0t, h1, N);
    gemm1_kernel<<<(N + 127) / 128, 256, 0, stream>>>(h1, B1t, bias, S, Q, N);
    final_kernel<<<(N + 255) / 256, 256, 0, stream>>>(S, Q, rowp, colb, outp, N);
}